// Round 5
// baseline (335.811 us; speedup 1.0000x reference)
//
#include <hip/hip_runtime.h>
#include <hip/hip_bf16.h>
#include <stdint.h>

// Problem constants
#define NB 16       // batch
#define NC 128      // C_in == C_out
#define NK 128      // modes
#define NSP 16384   // spatial N
#define SPLIT 32    // split-K chunks per batch for GEMM1
#define CHUNK 512   // NSP / SPLIT

typedef float f32x4 __attribute__((ext_vector_type(4)));
typedef __bf16 bf16x8 __attribute__((ext_vector_type(8)));

__device__ __forceinline__ unsigned short f32_to_bf16(float a) {
  unsigned int u = __float_as_uint(a);
  return (unsigned short)((u + 0x7fffu + ((u >> 16) & 1u)) >> 16);
}

__device__ __forceinline__ unsigned int pack_bf16(float a, float b) {
  unsigned int ua = __float_as_uint(a);
  unsigned int ub = __float_as_uint(b);
  ua = (ua + 0x7fffu + ((ua >> 16) & 1u)) >> 16;
  ub = (ub + 0x7fffu + ((ub >> 16) & 1u)) & 0xffff0000u;
  return ua | ub;
}

__device__ __forceinline__ bf16x8 pack8(float4 a0, float4 a1) {
  uint4 u;
  u.x = pack_bf16(a0.x, a0.y);
  u.y = pack_bf16(a0.z, a0.w);
  u.z = pack_bf16(a1.x, a1.y);
  u.w = pack_bf16(a1.z, a1.w);
  return __builtin_bit_cast(bf16x8, u);
}

// async global->LDS copy, 16 B per lane; LDS dst = base + lane*16 (wave-uniform base)
__device__ __forceinline__ void gl_lds16(const void* g, void* l) {
  __builtin_amdgcn_global_load_lds(
      (const __attribute__((address_space(1))) unsigned int*)g,
      (__attribute__((address_space(3))) unsigned int*)l, 16, 0, 0);
}

// ---------------------------------------------------------------------------
// k0: merged prep. Blocks 0..2047: wbases (NSP x NK) f32 -> wbT (NK x NSP) bf16
// (LDS tile transpose). Blocks 2048..4095: bases f32 -> bf16 straight convert.
__global__ void k0_prep(const float* __restrict__ wb, unsigned short* __restrict__ wbT,
                        const float* __restrict__ bases, unsigned short* __restrict__ bb) {
  __shared__ float tile[32][33];
  if (blockIdx.x < 2048) {
    int bid = blockIdx.x;
    int kt = (bid & 3) * 32;
    int nt = (bid >> 2) * 32;
    int tx = threadIdx.x & 31;
    int ty = threadIdx.x >> 5;  // 0..7
#pragma unroll
    for (int i = 0; i < 32; i += 8)
      tile[ty + i][tx] = wb[(size_t)(nt + ty + i) * NK + kt + tx];
    __syncthreads();
#pragma unroll
    for (int i = 0; i < 32; i += 8)
      wbT[(size_t)(kt + ty + i) * NSP + nt + tx] = f32_to_bf16(tile[tx][ty + i]);
  } else {
    int i = (blockIdx.x - 2048) * 256 + threadIdx.x;
    float4 v = ((const float4*)bases)[i];
    uint2 o;
    o.x = pack_bf16(v.x, v.y);
    o.y = pack_bf16(v.z, v.w);
    ((uint2*)bb)[i] = o;
  }
}

// ---------------------------------------------------------------------------
// k1 v6: split-K GEMM1. 3-buffer gl_lds pipeline with COUNTED vmcnt (T4):
// loads issued at step it are consumed at it+2 (2-step latency window);
// main loop never drains vmcnt to 0. Per step: {vmcnt(4); s_barrier;
// issue stage(it+2); compute(it)}. Hazards: RAW -> each wave waits its own
// stage(it) via vmcnt(4) BEFORE the barrier, so after the barrier all waves'
// tiles have landed. WAR -> stage(it+2) targets b[(it-1)%3]; every wave is
// past compute(it-1) when it reaches the barrier.
// Grid 1024 = chunk(32, fastest -> XCD affinity for wbT L2 reuse) x (b,chalf).
// Output 64c x 128k per block; x read exactly once. LDS 3 x 16 KB -> 3 blk/CU.
// Stores: operand-SWAPPED mfma(bf,af) puts v=0..3 along k -> f32x4 stores.
__global__ __launch_bounds__(256, 3)
void k1_proj(const float* __restrict__ x, const unsigned short* __restrict__ wbT,
             float* __restrict__ part) {
  int blk = blockIdx.x;
  int chunk = blk & 31;   // fastest -> blk%8 == chunk%8 (XCD affinity)
  int bc = blk >> 5;      // 0..31
  int b = bc >> 1;
  int chalf = bc & 1;
  int n0 = chunk * CHUNK;
  __shared__ __align__(16) char lds[3][16384];  // per buf: A 0..8K (64r x 128B swz), B 8K..16K (128r x 64B)
  int tid = threadIdx.x;
  int lane = tid & 63;
  int wave = tid >> 6;        // 0..3
  int cbw = (wave & 1) * 32;  // c sub-block within the 64-row half
  int kbw = (wave >> 1) * 64; // k half
  int r = lane & 15;
  int q = lane >> 4;

  f32x4 acc[2][4];
#pragma unroll
  for (int t = 0; t < 2; ++t)
#pragma unroll
    for (int u = 0; u < 4; ++u) acc[t][u] = (f32x4){0.f, 0.f, 0.f, 0.f};

  // A staging: instr i covers rows 8i..8i+7; lane -> row 8i+(lane>>3),
  // source col slot (16B) = (lane&7)^(row&7) [inverse swizzle, rule #21]
  const float* aptr = x + (size_t)(b * NC + chalf * 64 + (lane >> 3)) * NSP +
                      n0 + ((lane & 7) ^ (lane >> 3)) * 4;
  // B staging: instr i covers rows 16i..16i+15; lane -> row 16i+(lane>>2),
  // col slot = lane&3 (64 B rows; 8-phase-optimal reads, no swizzle needed)
  const unsigned short* bptr =
      wbT + (size_t)(lane >> 2) * NSP + n0 + (lane & 3) * 8;

#define K1_STAGE(st, buf)                                                     \
  {                                                                           \
    _Pragma("unroll") for (int j = 0; j < 2; ++j) {                           \
      int i = wave * 2 + j;                                                   \
      gl_lds16(aptr + (size_t)(8 * i) * NSP + (st) * 32, lds[buf] + i * 1024);\
      gl_lds16(bptr + (size_t)(16 * i) * NSP + (st) * 32,                     \
               lds[buf] + 8192 + i * 1024);                                   \
    }                                                                         \
  }

#define K1_COMPUTE(buf)                                                       \
  {                                                                           \
    const char* La = lds[buf];                                                \
    const char* Lb = lds[buf] + 8192;                                         \
    bf16x8 af[2], bf[4];                                                      \
    _Pragma("unroll") for (int t = 0; t < 2; ++t) {                           \
      int rw = cbw + 16 * t + r;                                              \
      float4 f0 =                                                             \
          *(const float4*)(La + rw * 128 + (((2 * q + 0) ^ (r & 7)) << 4));   \
      float4 f1 =                                                             \
          *(const float4*)(La + rw * 128 + (((2 * q + 1) ^ (r & 7)) << 4));   \
      af[t] = pack8(f0, f1);                                                  \
    }                                                                         \
    _Pragma("unroll") for (int u = 0; u < 4; ++u) {                           \
      int rk = kbw + 16 * u + r;                                              \
      bf[u] = *(const bf16x8*)(Lb + rk * 64 + q * 16);                        \
    }                                                                         \
    _Pragma("unroll") for (int t = 0; t < 2; ++t)                             \
        _Pragma("unroll") for (int u = 0; u < 4; ++u)                         \
        acc[t][u] = __builtin_amdgcn_mfma_f32_16x16x32_bf16(                  \
            bf[u], af[t], acc[t][u], 0, 0, 0);                                \
  }

  // prologue: two tiles in flight
  K1_STAGE(0, 0);
  K1_STAGE(1, 1);

#pragma unroll
  for (int it = 0; it < 15; ++it) {  // steps 0..14 (peel 15)
    asm volatile("s_waitcnt vmcnt(4)" ::: "memory");  // my stage(it) landed
    __builtin_amdgcn_s_barrier();                     // everyone's landed; compute(it-1) done
    asm volatile("" ::: "memory");
    if (it + 2 < 16) K1_STAGE(it + 2, (it + 2) % 3);
    K1_COMPUTE(it % 3);
  }
  asm volatile("s_waitcnt vmcnt(0)" ::: "memory");
  __builtin_amdgcn_s_barrier();
  asm volatile("" ::: "memory");
  K1_COMPUTE(0);  // it=15, 15%3==0
#undef K1_STAGE
#undef K1_COMPUTE

  // Swapped-operand C/D: acc[t][u][v] = D[k-row=4q+v][c-row=r]
  //   -> c = chalf*64+cbw+16t+r (fixed/lane), k = kbw+16u+4q+v (contig in v)
  float* pp = part + (size_t)(b * SPLIT + chunk) * (NC * NK);
#pragma unroll
  for (int t = 0; t < 2; ++t)
#pragma unroll
    for (int u = 0; u < 4; ++u)
      *(f32x4*)&pp[(size_t)(chalf * 64 + cbw + 16 * t + r) * NK + kbw + 16 * u +
                   4 * q] = acc[t][u];
}

// ---------------------------------------------------------------------------
// k1b: reduce SPLIT partials -> x_co fp32. float2-vectorized; 32 independent
// strided loads per thread = good MLP.
__global__ __launch_bounds__(256)
void k1b_reduce(const float* __restrict__ part, float* __restrict__ x_co) {
  int idx = blockIdx.x * 256 + threadIdx.x;  // 131072 float2 sites
  int b = idx >> 13;                         // / (NC*NK/2)
  int r2 = idx & 8191;
  const float2* p = (const float2*)(part + (size_t)b * SPLIT * (NC * NK)) + r2;
  float2 s = {0.f, 0.f};
#pragma unroll
  for (int c = 0; c < SPLIT; ++c) {
    float2 v = p[(size_t)c * (NC * NK / 2)];
    s.x += v.x;
    s.y += v.y;
  }
  ((float2*)x_co)[idx] = s;
}

// ---------------------------------------------------------------------------
// k2: per-mode channel mix, o-pair per block. Block = (b, o-pair), lanes = k.
// All operands L2/L3-resident (x_co 1 MB, W 8 MB). Fully coalesced.
__global__ __launch_bounds__(128)
void k2_mix(const float* __restrict__ x_co, const float* __restrict__ W,
            unsigned short* __restrict__ xhat_bf) {
  int b = blockIdx.x >> 6;          // 0..15
  int o0 = (blockIdx.x & 63) * 2;   // 0,2,..,126
  int k = threadIdx.x;
  const float* xc = x_co + (size_t)b * NC * NK + k;
  const float* w0 = W + (size_t)o0 * NK + k;
  float a0 = 0.f, a1 = 0.f;
#pragma unroll 4
  for (int i = 0; i < NC; ++i) {
    float v = xc[(size_t)i * NK];
    a0 += v * w0[(size_t)i * (NC * NK)];
    a1 += v * w0[(size_t)i * (NC * NK) + NK];
  }
  size_t base = ((size_t)b * NC + o0) * NK + k;
  xhat_bf[base] = f32_to_bf16(a0);
  xhat_bf[base + NK] = f32_to_bf16(a1);
}

// ---------------------------------------------------------------------------
// k3 v5: out (2048 x NSP) = xhat (2048 x 128) @ bases^T, LDS-free direct-load
// MFMA (operands L2-resident). v5: operand-SWAPPED mfma(bf,af) -> acc[t][u]
// holds 4 consecutive n per lane -> ONE f32x4 store per tile (was 4 scalar
// dword stores): 4x fewer store instrs, 16 rows x 64 B segments per instr.
__global__ __launch_bounds__(256, 4)
void k3_recon(const unsigned short* __restrict__ xhat_bf,
              const unsigned short* __restrict__ bases_bf,
              float* __restrict__ out) {
  int blk = blockIdx.x;
  int mo0 = (blk & 15) * 128;
  int n0 = (blk >> 4) * 256;
  int tid = threadIdx.x;
  int lane = tid & 63;
  int wave = tid >> 6;  // 0..3
  int mb = (wave & 1) * 64;
  int nb = (wave >> 1) * 64;
  int r = lane & 15;
  int q = lane >> 4;

  // A fragments: rows mo0+mb+16t+r, k = s*32+q*8 (L2-hot 16 B loads)
  bf16x8 af[4][4];
#pragma unroll
  for (int t = 0; t < 4; ++t)
#pragma unroll
    for (int s = 0; s < 4; ++s)
      af[t][s] = *(const bf16x8*)(xhat_bf +
                                  (size_t)(mo0 + mb + 16 * t + r) * NK +
                                  s * 32 + q * 8);

#pragma unroll
  for (int sub = 0; sub < 2; ++sub) {
    const unsigned short* brow =
        bases_bf + (size_t)(n0 + sub * 128 + nb + r) * NK + q * 8;
    f32x4 acc[4][4];
#pragma unroll
    for (int t = 0; t < 4; ++t)
#pragma unroll
      for (int u = 0; u < 4; ++u) acc[t][u] = (f32x4){0.f, 0.f, 0.f, 0.f};
#pragma unroll
    for (int s = 0; s < 4; ++s) {
      bf16x8 bf[4];
#pragma unroll
      for (int u = 0; u < 4; ++u)
        bf[u] = *(const bf16x8*)(brow + (size_t)u * 16 * NK + s * 32);
#pragma unroll
      for (int t = 0; t < 4; ++t)
#pragma unroll
        for (int u = 0; u < 4; ++u)
          acc[t][u] = __builtin_amdgcn_mfma_f32_16x16x32_bf16(
              bf[u], af[t][s], acc[t][u], 0, 0, 0);
    }
    // Swapped C/D: acc[t][u][v] = D[n-row=4q+v][m-row=r]
    //   -> m = mo0+mb+16t+r, n = n0+sub*128+nb+16u+4q+v (contig in v)
#pragma unroll
    for (int t = 0; t < 4; ++t)
#pragma unroll
      for (int u = 0; u < 4; ++u)
        *(f32x4*)&out[(size_t)(mo0 + mb + 16 * t + r) * NSP + n0 + sub * 128 +
                      nb + 16 * u + 4 * q] = acc[t][u];
  }
}

// ---------------------------------------------------------------------------
extern "C" void kernel_launch(void* const* d_in, const int* in_sizes, int n_in,
                              void* d_out, int out_size, void* d_ws, size_t ws_size,
                              hipStream_t stream) {
  const float* x = (const float*)d_in[0];       // (16,128,16384)
  const float* wbases = (const float*)d_in[1];  // (16384,128)
  const float* bases = (const float*)d_in[2];   // (16384,128)
  const float* W = (const float*)d_in[3];       // (128,128,128)
  float* out = (float*)d_out;                   // (16,128,16384)

  char* ws = (char*)d_ws;
  // ws layout (MB): wbT 0..4 | bases_bf 4..8 | part 8..40 | x_co 40..41 | xhat 41..41.5
  if (ws_size < ((size_t)42 << 20)) return;
  unsigned short* wbT = (unsigned short*)(ws);
  unsigned short* bases_bf = (unsigned short*)(ws + ((size_t)4 << 20));
  float* part = (float*)(ws + ((size_t)8 << 20));
  float* x_co = (float*)(ws + ((size_t)40 << 20));
  unsigned short* xhat_bf = (unsigned short*)(ws + ((size_t)41 << 20));

  k0_prep<<<4096, 256, 0, stream>>>(wbases, wbT, bases, bases_bf);
  k1_proj<<<1024, 256, 0, stream>>>(x, wbT, part);
  k1b_reduce<<<512, 256, 0, stream>>>(part, x_co);
  k2_mix<<<NB * NC / 2, 128, 0, stream>>>(x_co, W, xhat_bf);
  k3_recon<<<1024, 256, 0, stream>>>(xhat_bf, bases_bf, out);
}